// Round 7
// baseline (9791.319 us; speedup 1.0000x reference)
//
#include <hip/hip_runtime.h>
#include <hip/hip_bf16.h>

#define SEQ_LEN 48
#define HID     96
#define NB      131072
#define MROWS   304                    // 288 gate rows + 3 W_out rows + 13 zero pad
#define ABYTES  (MROWS*HID*2)          // 58368 B of bf16 A-fragments
#define COEF_OFF_F (ABYTES/4)          // float index 14592
#define COEF_FLOATS (96*16)            // stride-16 rows; quads rotated by (j>>2)&3 (injective)
#define BOUT_OFF_F (COEF_OFF_F + COEF_FLOATS)   // float idx 16128
#define LDS_U4  ((ABYTES + COEF_FLOATS*4)/16)   // 4032 uint4 = 64512 B

typedef __attribute__((ext_vector_type(4))) float f32x4;
typedef __attribute__((ext_vector_type(8))) __bf16 bf16x8;
typedef unsigned int uint;
typedef unsigned short ushort;

__device__ __forceinline__ float sigm(float x) {
    return __builtin_amdgcn_rcpf(1.f + __expf(-x));     // inf-safe
}
__device__ __forceinline__ float tanh_(float y) {
    return 1.f - 2.f * __builtin_amdgcn_rcpf(__expf(2.f * y) + 1.f);  // inf-safe
}
__device__ __forceinline__ uint packbf(float a, float b) {
    ushort lo = __builtin_bit_cast(ushort, __float2bfloat16(a));
    ushort hi = __builtin_bit_cast(ushort, __float2bfloat16(b));
    return (uint)lo | ((uint)hi << 16);
}

// ---------------- weight folding; coeff row quads rotated by q=(j>>2)&3 ------------------
// logical quads: L0=[wn0,wn1,wn2,bxn] L1=[bhhn,bsr,bsz,0] L2=[wr0,wr1,wr2,wz0] L3=[wz1,wz2,0,0]
// stored at position p = (L + q) & 3 within the row (reader un-rotates) -> bank-conflict-free.
__global__ void fold_k(const float* __restrict__ W_emb, const float* __restrict__ b_emb,
                       const float* __restrict__ W_ih,  const float* __restrict__ W_hh,
                       const float* __restrict__ b_ih,  const float* __restrict__ b_hh,
                       const float* __restrict__ W_out, const float* __restrict__ b_out,
                       void* wsv)
{
    ushort* A  = (ushort*)wsv;
    float*  CF = (float*)wsv + COEF_OFF_F;
    float*  BO = (float*)wsv + BOUT_OFF_F;
    int g = blockIdx.x * 64 + threadIdx.x;
    if (g < 3) BO[g] = b_out[g];

    auto wxe_row = [&](int gg, float* w, float& bx) {
        w[0] = w[1] = w[2] = 0.f; bx = b_ih[gg];
        for (int e = 0; e < 32; e++) {
            float wi = W_ih[gg * 32 + e];
            w[0] += wi * W_emb[e * 3 + 0];
            w[1] += wi * W_emb[e * 3 + 1];
            w[2] += wi * W_emb[e * 3 + 2];
            bx   += wi * b_emb[e];
        }
    };

    if (g < MROWS) {
        float w[3] = {0.f, 0.f, 0.f}, bx = 0.f;
        if (g < 192) wxe_row(g, w, bx);
        for (int k = 0; k < HID; k++) {
            float val;
            if      (g < 192) val = W_hh[g * HID + k] + w[0]*W_out[0*HID+k] + w[1]*W_out[1*HID+k] + w[2]*W_out[2*HID+k];
            else if (g < 288) val = W_hh[g * HID + k];
            else if (g < 291) val = W_out[(g - 288) * HID + k];
            else              val = 0.f;
            int t = g >> 4, c = k >> 5, l = (g & 15) | (((k >> 3) & 3) << 4), i = k & 7;
            A[((t * 3 + c) * 64 + l) * 8 + i] = __builtin_bit_cast(ushort, __float2bfloat16(val));
        }
    }
    if (g < 96) {
        int j = g;
        float wn[3], bxn; wxe_row(192 + j, wn, bxn);
        float wr[3], bxr; wxe_row(j,        wr, bxr);
        float wz[3], bxz; wxe_row(96 + j,   wz, bxz);
        float quads[4][4] = {
            { wn[0], wn[1], wn[2], bxn },
            { b_hh[192 + j],
              bxr + b_hh[j]      + wr[0]*b_out[0] + wr[1]*b_out[1] + wr[2]*b_out[2],
              bxz + b_hh[96 + j] + wz[0]*b_out[0] + wz[1]*b_out[1] + wz[2]*b_out[2],
              0.f },
            { wr[0], wr[1], wr[2], wz[0] },
            { wz[1], wz[2], 0.f, 0.f }
        };
        int qj = (j >> 2) & 3;
        float* row = CF + j * 16;
        for (int L = 0; L < 4; ++L) {
            int p = (L + qj) & 3;                  // rotate within own row: injective
            row[p * 4 + 0] = quads[L][0];
            row[p * 4 + 1] = quads[L][1];
            row[p * 4 + 2] = quads[L][2];
            row[p * 4 + 3] = quads[L][3];
        }
    }
}

// ---------------- main kernel: 16 cols/wave (nt=1) -> fits 128 VGPRs, no spills ----------
__global__ __launch_bounds__(256, 2)
void gru_mfma(const float* __restrict__ last_pos, const float* __restrict__ past,
              const float* __restrict__ fut, const void* __restrict__ wsv,
              float* __restrict__ out)
{
    __shared__ uint4 sb[LDS_U4];
    const int tid = threadIdx.x;
    const uint4* gsrc = (const uint4*)wsv;
    #pragma unroll
    for (int it = 0; it < 16; ++it) { int idx = tid + it * 256; if (idx < LDS_U4) sb[idx] = gsrc[idx]; }
    __syncthreads();

    const float* CF  = (const float*)sb + COEF_OFF_F;
    const float* BOg = (const float*)wsv + BOUT_OFF_F;
    const float bo[3] = {BOg[0], BOg[1], BOg[2]};

    const int lane = tid & 63;
    const int wid  = tid >> 6;                 // 0..3
    const int b    = lane & 15;
    const int q    = lane >> 4;
    const int rowbase = blockIdx.x * 64 + wid * 16;
    const int row0 = rowbase + b;

    // ---- h0 (bf16-packed, D-layout: lane holds h[16t+4q+r] for col b) ----
    uint hpk[6][2];
    #pragma unroll
    for (int t = 0; t < 6; ++t) {
        const float* src = (t < 3) ? (past + (size_t)row0 * 48 + t * 16 + q * 4)
                                   : (fut  + (size_t)row0 * 48 + (t - 3) * 16 + q * 4);
        f32x4 v = *(const f32x4*)src;
        hpk[t][0] = packbf(v[0], v[1]);
        hpk[t][1] = packbf(v[2], v[3]);
    }

    // ---- intra-wave exchange: D-layout hpk -> B-fragment ----
    const int idxA = 4 * (b | ((((q << 1) + 0) & 3) << 4));
    const int idxB = 4 * (b | ((((q << 1) + 1) & 3) << 4));
    uint4 bfu[3];
    auto do_exchange = [&]() {
        #pragma unroll
        for (int c = 0; c < 3; ++c)
            #pragma unroll
            for (int dd = 0; dd < 4; ++dd) {
                int idx = (dd < 2) ? idxA : idxB;
                int va = __builtin_amdgcn_ds_bpermute(idx, (int)hpk[2 * c][dd & 1]);
                int vb = __builtin_amdgcn_ds_bpermute(idx, (int)hpk[2 * c + 1][dd & 1]);
                bfu[c][dd] = (uint)((lane < 32) ? va : vb);
            }
    };
    do_exchange();

    // ---- p0 ----
    float pc[3];
    pc[0] = last_pos[(size_t)row0 * 3 + 0];
    pc[1] = last_pos[(size_t)row0 * 3 + 1];
    pc[2] = last_pos[(size_t)row0 * 3 + 2];

    const f32x4 zero4 = {0.f, 0.f, 0.f, 0.f};
    const int p0r = (0 + q) & 3, p1r = (1 + q) & 3, p2r = (2 + q) & 3, p3r = (3 + q) & 3;

    #pragma unroll 1
    for (int s = 0; s < SEQ_LEN; ++s) {
        // ---- tile 18 first: rel_pos_{s-1} -> p_s ----
        f32x4 a18;
        #pragma unroll
        for (int c = 0; c < 3; ++c) {
            bf16x8 a = __builtin_bit_cast(bf16x8, sb[(18 * 3 + c) * 64 + lane]);
            bf16x8 bb = __builtin_bit_cast(bf16x8, bfu[c]);
            a18 = __builtin_amdgcn_mfma_f32_16x16x32_bf16(a, bb, (c == 0) ? zero4 : a18, 0, 0, 0);
        }
        float d0[3];
        #pragma unroll
        for (int o = 0; o < 3; ++o) {
            float po = a18[o] + bo[o];
            float pb = __builtin_bit_cast(float,
                        __builtin_amdgcn_ds_bpermute(4 * b, __builtin_bit_cast(int, po)));
            if (s > 0) {
                if (q == 0) out[((size_t)(s - 1) * NB + row0) * 3 + o] = po;
                pc[o] = pb;
            } else {
                d0[o] = pc[o] - pb;            // step-0 folding correction
            }
        }
        __builtin_amdgcn_sched_barrier(0);

        // ---- 6 groups: {r,z,n} GEMM for rows 16t..16t+15, then immediate epilogue ----
        #pragma unroll
        for (int t = 0; t < 6; ++t) {
            f32x4 aR, aZ, aN;
            #pragma unroll
            for (int c = 0; c < 3; ++c) {
                bf16x8 fr = __builtin_bit_cast(bf16x8, sb[((t)      * 3 + c) * 64 + lane]);
                bf16x8 fz = __builtin_bit_cast(bf16x8, sb[((6 + t)  * 3 + c) * 64 + lane]);
                bf16x8 fn = __builtin_bit_cast(bf16x8, sb[((12 + t) * 3 + c) * 64 + lane]);
                bf16x8 bb = __builtin_bit_cast(bf16x8, bfu[c]);
                aR = __builtin_amdgcn_mfma_f32_16x16x32_bf16(fr, bb, (c == 0) ? zero4 : aR, 0, 0, 0);
                aZ = __builtin_amdgcn_mfma_f32_16x16x32_bf16(fz, bb, (c == 0) ? zero4 : aZ, 0, 0, 0);
                aN = __builtin_amdgcn_mfma_f32_16x16x32_bf16(fn, bb, (c == 0) ? zero4 : aN, 0, 0, 0);
            }
            const float* cbase = CF + (16 * t + 4 * q) * 16;   // rows r at +16r; quads un-rotated
            f32x4 ca[4], cb[4], c2[4], c3[4];
            #pragma unroll
            for (int r = 0; r < 4; ++r) {
                ca[r] = *(const f32x4*)(cbase + 16 * r + 4 * p0r);
                cb[r] = *(const f32x4*)(cbase + 16 * r + 4 * p1r);
                if (s == 0) {
                    c2[r] = *(const f32x4*)(cbase + 16 * r + 4 * p2r);
                    c3[r] = *(const f32x4*)(cbase + 16 * r + 4 * p3r);
                }
            }
            uint np0 = 0, np1 = 0;
            #pragma unroll
            for (int r = 0; r < 4; ++r) {
                float sr  = aR[r] + cb[r][1];
                float sz  = aZ[r] + cb[r][2];
                float ghn = aN[r] + cb[r][0];
                float gxn = ca[r][3] + pc[0]*ca[r][0] + pc[1]*ca[r][1] + pc[2]*ca[r][2];
                if (s == 0) {
                    sr += d0[0]*c2[r][0] + d0[1]*c2[r][1] + d0[2]*c2[r][2];
                    sz += d0[0]*c2[r][3] + d0[1]*c3[r][0] + d0[2]*c3[r][1];
                }
                float rg = sigm(sr);
                float zg = sigm(sz);
                float ng = tanh_(gxn + rg * ghn);
                uint pk = hpk[t][r >> 1];
                float hold = __builtin_bit_cast(float, (r & 1) ? (pk & 0xffff0000u) : (pk << 16));
                float hv = ng + zg * (hold - ng);
                ushort hb = __builtin_bit_cast(ushort, __float2bfloat16(hv));
                if      (r == 0) np0 = hb;
                else if (r == 1) np0 |= (uint)hb << 16;
                else if (r == 2) np1 = hb;
                else             np1 |= (uint)hb << 16;
            }
            hpk[t][0] = np0;
            hpk[t][1] = np1;
            __builtin_amdgcn_sched_barrier(0);
        }

        do_exchange();   // h_{s+1} -> B-fragment
    }

    // ---- final: rel_pos_47 = h_48 @ W_out^T + b_out ----
    f32x4 f18;
    #pragma unroll
    for (int c = 0; c < 3; ++c) {
        bf16x8 a = __builtin_bit_cast(bf16x8, sb[(18 * 3 + c) * 64 + lane]);
        bf16x8 bb = __builtin_bit_cast(bf16x8, bfu[c]);
        f18 = __builtin_amdgcn_mfma_f32_16x16x32_bf16(a, bb, (c == 0) ? zero4 : f18, 0, 0, 0);
    }
    if (q == 0) {
        #pragma unroll
        for (int o = 0; o < 3; ++o)
            out[((size_t)47 * NB + row0) * 3 + o] = f18[o] + bo[o];
    }
}

extern "C" void kernel_launch(void* const* d_in, const int* in_sizes, int n_in,
                              void* d_out, int out_size, void* d_ws, size_t ws_size,
                              hipStream_t stream)
{
    const float* last_pos = (const float*)d_in[0];
    const float* past     = (const float*)d_in[1];
    const float* fut      = (const float*)d_in[2];
    const float* W_emb    = (const float*)d_in[3];
    const float* b_emb    = (const float*)d_in[4];
    const float* W_ih     = (const float*)d_in[5];
    const float* W_hh     = (const float*)d_in[6];
    const float* b_ih     = (const float*)d_in[7];
    const float* b_hh     = (const float*)d_in[8];
    const float* W_out    = (const float*)d_in[9];
    const float* b_out    = (const float*)d_in[10];
    float* out = (float*)d_out;

    hipLaunchKernelGGL(fold_k, dim3(5), dim3(64), 0, stream,
                       W_emb, b_emb, W_ih, W_hh, b_ih, b_hh, W_out, b_out, d_ws);
    hipLaunchKernelGGL(gru_mfma, dim3(NB / 64), dim3(256), 0, stream,
                       last_pos, past, fut, d_ws, out);
}

// Round 8
// 842.716 us; speedup vs baseline: 11.6188x; 11.6188x over previous
//
#include <hip/hip_runtime.h>
#include <hip/hip_bf16.h>
#include <type_traits>

#define SEQ_LEN 48
#define HID     96
#define NB      131072
#define MROWS   304                    // 288 gate rows + 3 W_out rows + 13 zero pad
#define ABYTES  (MROWS*HID*2)          // 58368 B of bf16 A-fragments
#define COEF_OFF_F (ABYTES/4)          // float index 14592
#define COEF_FLOATS (96*16)            // stride-16 rows; quads rotated by (j>>2)&3 (injective)
#define BOUT_OFF_F (COEF_OFF_F + COEF_FLOATS)   // float idx 16128
#define LDS_U4  ((ABYTES + COEF_FLOATS*4)/16)   // 4032 uint4 = 64512 B

typedef __attribute__((ext_vector_type(4))) float f32x4;
typedef __attribute__((ext_vector_type(8))) __bf16 bf16x8;
typedef unsigned int uint;
typedef unsigned short ushort;

__device__ __forceinline__ float sigm(float x) {
    return __builtin_amdgcn_rcpf(1.f + __expf(-x));     // inf-safe
}
__device__ __forceinline__ float tanh_(float y) {
    return 1.f - 2.f * __builtin_amdgcn_rcpf(__expf(2.f * y) + 1.f);  // inf-safe
}
__device__ __forceinline__ uint packbf(float a, float b) {
    ushort lo = __builtin_bit_cast(ushort, __float2bfloat16(a));
    ushort hi = __builtin_bit_cast(ushort, __float2bfloat16(b));
    return (uint)lo | ((uint)hi << 16);
}

// ---------------- weight folding; coeff row quads rotated by q=(j>>2)&3 (r7-verified) ----
__global__ void fold_k(const float* __restrict__ W_emb, const float* __restrict__ b_emb,
                       const float* __restrict__ W_ih,  const float* __restrict__ W_hh,
                       const float* __restrict__ b_ih,  const float* __restrict__ b_hh,
                       const float* __restrict__ W_out, const float* __restrict__ b_out,
                       void* wsv)
{
    ushort* A  = (ushort*)wsv;
    float*  CF = (float*)wsv + COEF_OFF_F;
    float*  BO = (float*)wsv + BOUT_OFF_F;
    int g = blockIdx.x * 64 + threadIdx.x;
    if (g < 3) BO[g] = b_out[g];

    auto wxe_row = [&](int gg, float* w, float& bx) {
        w[0] = w[1] = w[2] = 0.f; bx = b_ih[gg];
        for (int e = 0; e < 32; e++) {
            float wi = W_ih[gg * 32 + e];
            w[0] += wi * W_emb[e * 3 + 0];
            w[1] += wi * W_emb[e * 3 + 1];
            w[2] += wi * W_emb[e * 3 + 2];
            bx   += wi * b_emb[e];
        }
    };

    if (g < MROWS) {
        float w[3] = {0.f, 0.f, 0.f}, bx = 0.f;
        if (g < 192) wxe_row(g, w, bx);
        for (int k = 0; k < HID; k++) {
            float val;
            if      (g < 192) val = W_hh[g * HID + k] + w[0]*W_out[0*HID+k] + w[1]*W_out[1*HID+k] + w[2]*W_out[2*HID+k];
            else if (g < 288) val = W_hh[g * HID + k];
            else if (g < 291) val = W_out[(g - 288) * HID + k];
            else              val = 0.f;
            int t = g >> 4, c = k >> 5, l = (g & 15) | (((k >> 3) & 3) << 4), i = k & 7;
            A[((t * 3 + c) * 64 + l) * 8 + i] = __builtin_bit_cast(ushort, __float2bfloat16(val));
        }
    }
    if (g < 96) {
        int j = g;
        float wn[3], bxn; wxe_row(192 + j, wn, bxn);
        float wr[3], bxr; wxe_row(j,        wr, bxr);
        float wz[3], bxz; wxe_row(96 + j,   wz, bxz);
        float quads[4][4] = {
            { wn[0], wn[1], wn[2], bxn },
            { b_hh[192 + j],
              bxr + b_hh[j]      + wr[0]*b_out[0] + wr[1]*b_out[1] + wr[2]*b_out[2],
              bxz + b_hh[96 + j] + wz[0]*b_out[0] + wz[1]*b_out[1] + wz[2]*b_out[2],
              0.f },
            { wr[0], wr[1], wr[2], wz[0] },
            { wz[1], wz[2], 0.f, 0.f }
        };
        int qj = (j >> 2) & 3;
        float* row = CF + j * 16;
        for (int L = 0; L < 4; ++L) {
            int p = (L + qj) & 3;                  // rotate within own row: injective
            row[p * 4 + 0] = quads[L][0];
            row[p * 4 + 1] = quads[L][1];
            row[p * 4 + 2] = quads[L][2];
            row[p * 4 + 3] = quads[L][3];
        }
    }
}

// ---------------- main kernel: s=0 peeled so steady loop has NO c2/c3 liveness ----------
__global__ __launch_bounds__(256, 2)
void gru_mfma(const float* __restrict__ last_pos, const float* __restrict__ past,
              const float* __restrict__ fut, const void* __restrict__ wsv,
              float* __restrict__ out)
{
    __shared__ uint4 sb[LDS_U4];
    const int tid = threadIdx.x;
    const uint4* gsrc = (const uint4*)wsv;
    #pragma unroll
    for (int it = 0; it < 16; ++it) { int idx = tid + it * 256; if (idx < LDS_U4) sb[idx] = gsrc[idx]; }
    __syncthreads();

    const float* CF  = (const float*)sb + COEF_OFF_F;
    const float* BOg = (const float*)wsv + BOUT_OFF_F;
    const float bo[3] = {BOg[0], BOg[1], BOg[2]};

    const int lane = tid & 63;
    const int wid  = tid >> 6;                 // 0..3
    const int b    = lane & 15;
    const int q    = lane >> 4;
    const int row0 = blockIdx.x * 64 + wid * 16 + b;

    // ---- h0 (bf16-packed, D-layout: lane holds h[16t+4q+r] for col b) ----
    uint hpk[6][2];
    #pragma unroll
    for (int t = 0; t < 6; ++t) {
        const float* src = (t < 3) ? (past + (size_t)row0 * 48 + t * 16 + q * 4)
                                   : (fut  + (size_t)row0 * 48 + (t - 3) * 16 + q * 4);
        f32x4 v = *(const f32x4*)src;
        hpk[t][0] = packbf(v[0], v[1]);
        hpk[t][1] = packbf(v[2], v[3]);
    }

    // ---- intra-wave exchange: D-layout hpk -> B-fragment ----
    const int idxA = 4 * (b | ((((q << 1) + 0) & 3) << 4));
    const int idxB = 4 * (b | ((((q << 1) + 1) & 3) << 4));
    uint4 bfu[3];
    auto do_exchange = [&]() {
        #pragma unroll
        for (int c = 0; c < 3; ++c)
            #pragma unroll
            for (int dd = 0; dd < 4; ++dd) {
                int idx = (dd < 2) ? idxA : idxB;
                int va = __builtin_amdgcn_ds_bpermute(idx, (int)hpk[2 * c][dd & 1]);
                int vb = __builtin_amdgcn_ds_bpermute(idx, (int)hpk[2 * c + 1][dd & 1]);
                bfu[c][dd] = (uint)((lane < 32) ? va : vb);
            }
    };
    do_exchange();

    // ---- p0 ----
    float pc[3];
    pc[0] = last_pos[(size_t)row0 * 3 + 0];
    pc[1] = last_pos[(size_t)row0 * 3 + 1];
    pc[2] = last_pos[(size_t)row0 * 3 + 2];

    const f32x4 zero4 = {0.f, 0.f, 0.f, 0.f};
    const int p0r = (0 + q) & 3, p1r = (1 + q) & 3, p2r = (2 + q) & 3, p3r = (3 + q) & 3;

    // tile-18 mini-GEMM (p-path), used in peel, steady loop, and finale
    auto tile18 = [&]() -> f32x4 {
        f32x4 a18;
        #pragma unroll
        for (int c = 0; c < 3; ++c) {
            bf16x8 a = __builtin_bit_cast(bf16x8, sb[(18 * 3 + c) * 64 + lane]);
            bf16x8 bb = __builtin_bit_cast(bf16x8, bfu[c]);
            a18 = __builtin_amdgcn_mfma_f32_16x16x32_bf16(a, bb, (c == 0) ? zero4 : a18, 0, 0, 0);
        }
        return a18;
    };

    // 6 gate groups; FIRST selects the (compile-time) step-0 correction path
    auto do_groups = [&](auto FIRST_c, const float* d0) {
        constexpr bool FIRST = decltype(FIRST_c)::value;
        #pragma unroll
        for (int t = 0; t < 6; ++t) {
            f32x4 aR, aZ, aN;
            #pragma unroll
            for (int c = 0; c < 3; ++c) {
                bf16x8 fr = __builtin_bit_cast(bf16x8, sb[((t)      * 3 + c) * 64 + lane]);
                bf16x8 fz = __builtin_bit_cast(bf16x8, sb[((6 + t)  * 3 + c) * 64 + lane]);
                bf16x8 fn = __builtin_bit_cast(bf16x8, sb[((12 + t) * 3 + c) * 64 + lane]);
                bf16x8 bb = __builtin_bit_cast(bf16x8, bfu[c]);
                aR = __builtin_amdgcn_mfma_f32_16x16x32_bf16(fr, bb, (c == 0) ? zero4 : aR, 0, 0, 0);
                aZ = __builtin_amdgcn_mfma_f32_16x16x32_bf16(fz, bb, (c == 0) ? zero4 : aZ, 0, 0, 0);
                aN = __builtin_amdgcn_mfma_f32_16x16x32_bf16(fn, bb, (c == 0) ? zero4 : aN, 0, 0, 0);
            }
            const float* cbase = CF + (16 * t + 4 * q) * 16;   // rows r at +16r; quads un-rotated
            uint np0 = 0, np1 = 0;
            #pragma unroll
            for (int r = 0; r < 4; ++r) {
                f32x4 ca = *(const f32x4*)(cbase + 16 * r + 4 * p0r);
                f32x4 cb = *(const f32x4*)(cbase + 16 * r + 4 * p1r);
                float sr  = aR[r] + cb[1];
                float sz  = aZ[r] + cb[2];
                float ghn = aN[r] + cb[0];
                float gxn = ca[3] + pc[0]*ca[0] + pc[1]*ca[1] + pc[2]*ca[2];
                if constexpr (FIRST) {
                    f32x4 c2 = *(const f32x4*)(cbase + 16 * r + 4 * p2r);
                    f32x4 c3 = *(const f32x4*)(cbase + 16 * r + 4 * p3r);
                    sr += d0[0]*c2[0] + d0[1]*c2[1] + d0[2]*c2[2];
                    sz += d0[0]*c2[3] + d0[1]*c3[0] + d0[2]*c3[1];
                }
                float rg = sigm(sr);
                float zg = sigm(sz);
                float ng = tanh_(gxn + rg * ghn);
                uint pk = hpk[t][r >> 1];
                float hold = __builtin_bit_cast(float, (r & 1) ? (pk & 0xffff0000u) : (pk << 16));
                float hv = ng + zg * (hold - ng);
                ushort hb = __builtin_bit_cast(ushort, __float2bfloat16(hv));
                if      (r == 0) np0 = hb;
                else if (r == 1) np0 |= (uint)hb << 16;
                else if (r == 2) np1 = hb;
                else             np1 |= (uint)hb << 16;
            }
            hpk[t][0] = np0;
            hpk[t][1] = np1;
            __builtin_amdgcn_sched_barrier(0);
        }
    };

    // ================= peeled step 0 (has the folding correction) =================
    {
        f32x4 a18 = tile18();
        float d0[3];
        #pragma unroll
        for (int o = 0; o < 3; ++o) {
            float po = a18[o] + bo[o];
            float pb = __builtin_bit_cast(float,
                        __builtin_amdgcn_ds_bpermute(4 * b, __builtin_bit_cast(int, po)));
            d0[o] = pc[o] - pb;                 // p0 - p~0
        }
        __builtin_amdgcn_sched_barrier(0);
        do_groups(std::integral_constant<bool, true>{}, d0);
        do_exchange();
    }

    // ================= steady loop s = 1..47 (no correction, no branches) =========
    #pragma unroll 1
    for (int s = 1; s < SEQ_LEN; ++s) {
        f32x4 a18 = tile18();
        #pragma unroll
        for (int o = 0; o < 3; ++o) {
            float po = a18[o] + bo[o];
            float pb = __builtin_bit_cast(float,
                        __builtin_amdgcn_ds_bpermute(4 * b, __builtin_bit_cast(int, po)));
            if (q == 0) out[((size_t)(s - 1) * NB + row0) * 3 + o] = po;
            pc[o] = pb;
        }
        __builtin_amdgcn_sched_barrier(0);
        do_groups(std::integral_constant<bool, false>{}, nullptr);
        do_exchange();
    }

    // ================= final: rel_pos_47 ==========================================
    {
        f32x4 f18 = tile18();
        if (q == 0) {
            #pragma unroll
            for (int o = 0; o < 3; ++o)
                out[((size_t)47 * NB + row0) * 3 + o] = f18[o] + bo[o];
        }
    }
}

extern "C" void kernel_launch(void* const* d_in, const int* in_sizes, int n_in,
                              void* d_out, int out_size, void* d_ws, size_t ws_size,
                              hipStream_t stream)
{
    const float* last_pos = (const float*)d_in[0];
    const float* past     = (const float*)d_in[1];
    const float* fut      = (const float*)d_in[2];
    const float* W_emb    = (const float*)d_in[3];
    const float* b_emb    = (const float*)d_in[4];
    const float* W_ih     = (const float*)d_in[5];
    const float* W_hh     = (const float*)d_in[6];
    const float* b_ih     = (const float*)d_in[7];
    const float* b_hh     = (const float*)d_in[8];
    const float* W_out    = (const float*)d_in[9];
    const float* b_out    = (const float*)d_in[10];
    float* out = (float*)d_out;

    hipLaunchKernelGGL(fold_k, dim3(5), dim3(64), 0, stream,
                       W_emb, b_emb, W_ih, W_hh, b_ih, b_hh, W_out, b_out, d_ws);
    hipLaunchKernelGGL(gru_mfma, dim3(NB / 64), dim3(256), 0, stream,
                       last_pos, past, fut, d_ws, out);
}